// Round 4
// baseline (161.262 us; speedup 1.0000x reference)
//
#include <hip/hip_runtime.h>
#include <hip/hip_bf16.h>

#define BB 16
#define LL 4096
#define CC 512
#define NG 128   // B*G
#define IC1 68
#define OC1 64
#define OC2 32

typedef short short8 __attribute__((ext_vector_type(8)));
typedef float f32x4 __attribute__((ext_vector_type(4)));

__device__ inline ushort f2b(float f) {
    __hip_bfloat16 h = __float2bfloat16(f);
    return *reinterpret_cast<ushort*>(&h);
}
__device__ inline float b2f(ushort u) {
    __hip_bfloat16 h;
    *reinterpret_cast<ushort*>(&h) = u;
    return __bfloat162float(h);
}
__device__ inline float fast_tanh(float y) {
    float e = __expf(2.0f * y);
    return 1.0f - 2.0f / (e + 1.0f);
}
__device__ inline float fast_gelu(float x) {
    float y = x * (0.7978845608f + 0.0356774081f * x * x);
    return 0.5f * x * (1.0f + fast_tanh(y));
}

// ---------------- prep: bf16 weights (padded), corr ----------------
__global__ __launch_bounds__(256) void k_prep(const float* __restrict__ x,
    const float* __restrict__ w1, const float* __restrict__ w2,
    const float* __restrict__ gate,
    ushort* __restrict__ w1b, ushort* __restrict__ w2b, float* __restrict__ corr)
{
    int idx = blockIdx.x * 256 + threadIdx.x;
    if (idx < 18432) {                       // w1b[k][oc][icp<96]
        int k = idx / 6144; int r = idx - k * 6144;
        int oc = r / 96;    int icp = r - oc * 96;
        float v = (icp < IC1) ? w1[(oc * IC1 + icp) * 3 + k] : 0.0f;
        w1b[idx] = f2b(v);
    } else if (idx < 24576) {                // w2b[k][oc][ic<64]
        int j = idx - 18432;
        int k = j / 2048; int r = j - k * 2048;
        int oc = r / 64;  int ic = r - oc * 64;
        w2b[j] = f2b(w2[(oc * OC1 + ic) * 3 + k]);
    } else if (idx < 32768) {                // corr[b*512+ch]
        int i3 = idx - 24576;
        int b = i3 >> 9; int ch = i3 & 511;
        float tg = tanhf(gate[0]);
        corr[i3] = tg * 0.5f *
            (x[((size_t)(b * LL + 2047)) * CC + ch] +
             x[((size_t)(b * LL + 2048)) * CC + ch]);
    }
}

// ---------------- A: conv1 via MFMA -> group sums only ----------------
#define K1_ROWS 130
#define K1_STR  104   // ushorts per row (208 B = 13 x 16B)
__global__ __launch_bounds__(256) void ka_stats(const float* __restrict__ x,
    const float* __restrict__ xe, const float* __restrict__ b1,
    const ushort* __restrict__ w1b, float* __restrict__ part)
{
    __shared__ ushort pin[K1_ROWS * K1_STR];   // 27040 B
    const int n = blockIdx.y, lt = blockIdx.x;
    const int b = n >> 3, g = n & 7, be = n & 15;
    const int l0 = lt * 128;
    const int t = threadIdx.x;

    {
        const int q = t & 15;
        for (int pos = t; pos < K1_ROWS * 16; pos += 256) {
            int li = pos >> 4;
            int l = l0 - 1 + li;
            float4 v = make_float4(0.f, 0.f, 0.f, 0.f);
            if (l >= 0 && l < LL)
                v = *(const float4*)&x[((size_t)(b * LL + l)) * CC + g * 64 + q * 4];
            uint lo = (uint)f2b(v.x) | ((uint)f2b(v.y) << 16);
            uint hi = (uint)f2b(v.z) | ((uint)f2b(v.w) << 16);
            *(uint2*)&pin[li * K1_STR + q * 4] = make_uint2(lo, hi);
        }
    }
    for (int li = t; li < K1_ROWS; li += 256) {
        int l = l0 - 1 + li;
        float4 v = make_float4(0.f, 0.f, 0.f, 0.f);
        if (l >= 0 && l < LL)
            v = *(const float4*)&xe[(size_t)(be * LL + l) * 4];
        uint lo = (uint)f2b(v.x) | ((uint)f2b(v.y) << 16);
        uint hi = (uint)f2b(v.z) | ((uint)f2b(v.w) << 16);
        *(uint2*)&pin[li * K1_STR + 64] = make_uint2(lo, hi);
    }
    {
        uint* pz = (uint*)pin;
        for (int pos = t; pos < K1_ROWS * 14; pos += 256) {
            int li = pos / 14, j = pos - li * 14;
            pz[li * 52 + 34 + j] = 0u;
        }
    }
    __syncthreads();

    const int lane = t & 63;
    const int w = t >> 6;
    const int och = w & 1, lh = w >> 1;
    const int m = lane & 15, h = lane >> 4;

    short8 fa[2][9];
#pragma unroll
    for (int mi = 0; mi < 2; ++mi)
#pragma unroll
        for (int k = 0; k < 3; ++k)
#pragma unroll
            for (int c = 0; c < 3; ++c)
                fa[mi][k * 3 + c] = *(const short8*)&w1b[
                    (size_t)(k * 64 + och * 32 + mi * 16 + m) * 96 + c * 32 + h * 8];

    f32x4 acc[2][4] = {};
#pragma unroll
    for (int tt = 0; tt < 4; ++tt) {
        const int rowbase = lh * 64 + tt * 16 + m;
#pragma unroll
        for (int k = 0; k < 3; ++k) {
#pragma unroll
            for (int c = 0; c < 3; ++c) {
                short8 fb = *(const short8*)&pin[(rowbase + k) * K1_STR + c * 32 + h * 8];
                acc[0][tt] = __builtin_amdgcn_mfma_f32_16x16x32_bf16(fa[0][k * 3 + c], fb, acc[0][tt], 0, 0, 0);
                acc[1][tt] = __builtin_amdgcn_mfma_f32_16x16x32_bf16(fa[1][k * 3 + c], fb, acc[1][tt], 0, 0, 0);
            }
        }
    }

#pragma unroll
    for (int mi = 0; mi < 2; ++mi) {
        float bias[4];
#pragma unroll
        for (int r = 0; r < 4; ++r)
            bias[r] = b1[och * 32 + mi * 16 + h * 4 + r];
        float s1 = 0.f, s2 = 0.f;
#pragma unroll
        for (int tt = 0; tt < 4; ++tt) {
            float v0 = acc[mi][tt][0] + bias[0];
            float v1 = acc[mi][tt][1] + bias[1];
            float v2 = acc[mi][tt][2] + bias[2];
            float v3 = acc[mi][tt][3] + bias[3];
            s1 += v0 + v1 + v2 + v3;
            s2 += v0 * v0 + v1 * v1 + v2 * v2 + v3 * v3;
        }
#pragma unroll
        for (int off = 32; off > 0; off >>= 1) {
            s1 += __shfl_down(s1, off, 64);
            s2 += __shfl_down(s2, off, 64);
        }
        if (lane == 0) {
            int gidx = och * 2 + mi;   // GN group (oc>>4)
            part[(((size_t)n * 4 + gidx) * 64 + lt * 2 + lh) * 2 + 0] = s1;
            part[(((size_t)n * 4 + gidx) * 64 + lt * 2 + lh) * 2 + 1] = s2;
        }
    }
}

// ---------------- B: fully fused second pass ----------------
// outputs offs at l in [l0, l0+124); h2 pos j=0..127 <-> l=l0-1+j;
// h pos p=0..127 <-> l=l0-2+p; x rows li=0..129 <-> l=l0-3+li
#define BT 124
#define XR 130
#define P2R 130
#define P2STR 72    // 144 B = 9 x 16B
#define H2STR 132
__global__ __launch_bounds__(256) void kb_fused(const float* __restrict__ x,
    const float* __restrict__ xe, const float* __restrict__ b1,
    const ushort* __restrict__ w1b, const float* __restrict__ part,
    const float* __restrict__ gn_g, const float* __restrict__ gn_b,
    const float* __restrict__ b2, const ushort* __restrict__ w2b,
    const float* __restrict__ w3, const float* __restrict__ corr,
    float* __restrict__ out, float* __restrict__ offs)
{
    __shared__ ushort pin[XR * K1_STR];    // 27040 B (aliased as h2s later)
    __shared__ ushort p2[P2R * P2STR];     // 18720 B
    __shared__ float sstats[8];
    const int n = blockIdx.y, lt = blockIdx.x;
    const int b = n >> 3, g = n & 7, be = n & 15;
    const int l0 = lt * BT;
    const int t = threadIdx.x;
    const int lane = t & 63;
    const int w = t >> 6;

    // stats: wave w reduces GN group w (2 KB, L2-hot)
    {
        float2 p = *(const float2*)&part[(((size_t)n * 4 + w) * 64 + lane) * 2];
        float s1 = p.x, s2 = p.y;
#pragma unroll
        for (int off = 32; off > 0; off >>= 1) {
            s1 += __shfl_down(s1, off, 64);
            s2 += __shfl_down(s2, off, 64);
        }
        if (lane == 0) {
            float mean = s1 * (1.0f / 65536.0f);
            float var  = s2 * (1.0f / 65536.0f) - mean * mean;
            sstats[w * 2 + 0] = mean;
            sstats[w * 2 + 1] = 1.0f / sqrtf(var + 1e-5f);
        }
    }

    // phase 1: stage x -> pin (bf16) + fused out = x + corr
    {
        const int q = t & 15;
        const float4 corrv = *(const float4*)&corr[(b << 9) + g * 64 + q * 4];
        for (int pos = t; pos < XR * 16; pos += 256) {
            int li = pos >> 4;
            int l = l0 - 3 + li;
            float4 v = make_float4(0.f, 0.f, 0.f, 0.f);
            if (l >= 0 && l < LL) {
                v = *(const float4*)&x[((size_t)(b * LL + l)) * CC + g * 64 + q * 4];
                if (li >= 3 && li < 3 + BT) {   // l in [l0, l0+BT)
                    float4 o;
                    o.x = v.x + corrv.x; o.y = v.y + corrv.y;
                    o.z = v.z + corrv.z; o.w = v.w + corrv.w;
                    *(float4*)&out[((size_t)(b * LL + l)) * CC + g * 64 + q * 4] = o;
                }
            }
            uint lo = (uint)f2b(v.x) | ((uint)f2b(v.y) << 16);
            uint hi = (uint)f2b(v.z) | ((uint)f2b(v.w) << 16);
            *(uint2*)&pin[li * K1_STR + q * 4] = make_uint2(lo, hi);
        }
        for (int li = t; li < XR; li += 256) {
            int l = l0 - 3 + li;
            float4 v = make_float4(0.f, 0.f, 0.f, 0.f);
            if (l >= 0 && l < LL)
                v = *(const float4*)&xe[(size_t)(be * LL + l) * 4];
            uint lo = (uint)f2b(v.x) | ((uint)f2b(v.y) << 16);
            uint hi = (uint)f2b(v.z) | ((uint)f2b(v.w) << 16);
            *(uint2*)&pin[li * K1_STR + 64] = make_uint2(lo, hi);
        }
        uint* pz = (uint*)pin;
        for (int pos = t; pos < XR * 14; pos += 256) {
            int li = pos / 14, j = pos - li * 14;
            pz[li * 52 + 34 + j] = 0u;
        }
        uint* qz = (uint*)p2;
        for (int i = t; i < 72; i += 256)      // zero p2 rows 128,129
            qz[128 * 36 + i] = 0u;
    }
    __syncthreads();

    // phase 2: conv1 MFMA (recompute)
    const int och = w & 1, lh = w >> 1;
    const int m = lane & 15, h = lane >> 4;

    short8 fa[2][9];
#pragma unroll
    for (int mi = 0; mi < 2; ++mi)
#pragma unroll
        for (int k = 0; k < 3; ++k)
#pragma unroll
            for (int c = 0; c < 3; ++c)
                fa[mi][k * 3 + c] = *(const short8*)&w1b[
                    (size_t)(k * 64 + och * 32 + mi * 16 + m) * 96 + c * 32 + h * 8];

    f32x4 acc[2][4] = {};
#pragma unroll
    for (int tt = 0; tt < 4; ++tt) {
        const int rowbase = lh * 64 + tt * 16 + m;   // = h-position p; x row = p + k
#pragma unroll
        for (int k = 0; k < 3; ++k) {
#pragma unroll
            for (int c = 0; c < 3; ++c) {
                short8 fb = *(const short8*)&pin[(rowbase + k) * K1_STR + c * 32 + h * 8];
                acc[0][tt] = __builtin_amdgcn_mfma_f32_16x16x32_bf16(fa[0][k * 3 + c], fb, acc[0][tt], 0, 0, 0);
                acc[1][tt] = __builtin_amdgcn_mfma_f32_16x16x32_bf16(fa[1][k * 3 + c], fb, acc[1][tt], 0, 0, 0);
            }
        }
    }

    // phase 3: bias+GN+GELU -> p2[p][oc] (bf16), zero outside [0,LL)
#pragma unroll
    for (int mi = 0; mi < 2; ++mi) {
        int gi = och * 2 + mi;
        float mean = sstats[gi * 2], istd = sstats[gi * 2 + 1];
        float A_[4], B_[4];
#pragma unroll
        for (int r = 0; r < 4; ++r) {
            int oc = och * 32 + mi * 16 + h * 4 + r;
            float ga = gn_g[oc];
            A_[r] = istd * ga;
            B_[r] = gn_b[oc] + (b1[oc] - mean) * A_[r];
        }
#pragma unroll
        for (int tt = 0; tt < 4; ++tt) {
            int p = lh * 64 + tt * 16 + m;
            int l = l0 - 2 + p;
            uint2 pk = make_uint2(0u, 0u);
            if (l >= 0 && l < LL) {
                float v0 = fast_gelu(fmaf(acc[mi][tt][0], A_[0], B_[0]));
                float v1 = fast_gelu(fmaf(acc[mi][tt][1], A_[1], B_[1]));
                float v2 = fast_gelu(fmaf(acc[mi][tt][2], A_[2], B_[2]));
                float v3 = fast_gelu(fmaf(acc[mi][tt][3], A_[3], B_[3]));
                pk.x = (uint)f2b(v0) | ((uint)f2b(v1) << 16);
                pk.y = (uint)f2b(v2) | ((uint)f2b(v3) << 16);
            }
            *(uint2*)&p2[p * P2STR + och * 32 + mi * 16 + h * 4] = pk;
        }
    }
    __syncthreads();

    // phase 4: conv2 MFMA + GELU -> h2s (aliased over pin)
    short8 fa2[2][6];
#pragma unroll
    for (int mi = 0; mi < 2; ++mi)
#pragma unroll
        for (int k = 0; k < 3; ++k)
#pragma unroll
            for (int c = 0; c < 2; ++c)
                fa2[mi][k * 2 + c] = *(const short8*)&w2b[
                    (size_t)(k * 32 + mi * 16 + m) * 64 + c * 32 + h * 8];

    float bias2[2][4];
#pragma unroll
    for (int mi = 0; mi < 2; ++mi)
#pragma unroll
        for (int r = 0; r < 4; ++r)
            bias2[mi][r] = b2[mi * 16 + h * 4 + r];

    f32x4 acc2[2][2] = {};
#pragma unroll
    for (int u = 0; u < 2; ++u) {
        const int jb = (w * 2 + u) * 16 + m;     // h2 col j
#pragma unroll
        for (int k = 0; k < 3; ++k) {
#pragma unroll
            for (int c = 0; c < 2; ++c) {
                short8 fb = *(const short8*)&p2[(jb + k) * P2STR + c * 32 + h * 8];
                acc2[0][u] = __builtin_amdgcn_mfma_f32_16x16x32_bf16(fa2[0][k * 2 + c], fb, acc2[0][u], 0, 0, 0);
                acc2[1][u] = __builtin_amdgcn_mfma_f32_16x16x32_bf16(fa2[1][k * 2 + c], fb, acc2[1][u], 0, 0, 0);
            }
        }
    }
    float* h2s = (float*)pin;   // pin reads all done (barrier after phase 3)
#pragma unroll
    for (int mi = 0; mi < 2; ++mi) {
#pragma unroll
        for (int u = 0; u < 2; ++u) {
            int j = (w * 2 + u) * 16 + m;
            int lj = l0 - 1 + j;
#pragma unroll
            for (int r = 0; r < 4; ++r) {
                int oc = mi * 16 + h * 4 + r;
                float v = 0.f;
                if (lj >= 0 && lj < LL)
                    v = fast_gelu(acc2[mi][u][r] + bias2[mi][r]);
                h2s[oc * H2STR + j] = v;
            }
        }
    }
    __syncthreads();

    // phase 5: conv3 + tanh*10 -> offs
    for (int qq = t; qq < BT; qq += 256) {
        int l = l0 + qq;
        if (l >= LL) break;
        float a = 0.f;
#pragma unroll
        for (int ic = 0; ic < OC2; ++ic) {
            a = fmaf(w3[ic * 3 + 0], h2s[ic * H2STR + qq],     a);
            a = fmaf(w3[ic * 3 + 1], h2s[ic * H2STR + qq + 1], a);
            a = fmaf(w3[ic * 3 + 2], h2s[ic * H2STR + qq + 2], a);
        }
        offs[(size_t)n * LL + l] = fast_tanh(a) * 10.0f;
    }
}

extern "C" void kernel_launch(void* const* d_in, const int* in_sizes, int n_in,
                              void* d_out, int out_size, void* d_ws, size_t ws_size,
                              hipStream_t stream)
{
    const float* x    = (const float*)d_in[0];
    const float* xext = (const float*)d_in[1];
    const float* w1   = (const float*)d_in[2];
    const float* b1   = (const float*)d_in[3];
    const float* gng  = (const float*)d_in[4];
    const float* gnb  = (const float*)d_in[5];
    const float* w2   = (const float*)d_in[6];
    const float* b2   = (const float*)d_in[7];
    const float* w3   = (const float*)d_in[8];
    const float* gate = (const float*)d_in[9];

    float* out  = (float*)d_out;
    float* offs = out + (size_t)BB * LL * CC;        // 33,554,432

    char* ws = (char*)d_ws;
    float* part = (float*)(ws);                      // 262,144 B
    ushort* w1b = (ushort*)(ws + 262144);            // 36,864 B
    ushort* w2b = (ushort*)(ws + 299008);            // 12,288 B
    float* corr = (float*)(ws + 311296);             // 32,768 B

    k_prep<<<128, 256, 0, stream>>>(x, w1, w2, gate, w1b, w2b, corr);
    dim3 g1(32, NG);
    ka_stats<<<g1, 256, 0, stream>>>(x, xext, b1, w1b, part);
    dim3 g3(34, NG);
    kb_fused<<<g3, 256, 0, stream>>>(x, xext, b1, w1b, part, gng, gnb, b2, w2b,
                                     w3, corr, out, offs);
}